// Round 1
// baseline (256.309 us; speedup 1.0000x reference)
//
#include <hip/hip_runtime.h>
#include <hip/hip_fp16.h>

#define SEQ 2048
#define NBH 32

typedef _Float16 f16x8 __attribute__((ext_vector_type(8)));
typedef float f32x4 __attribute__((ext_vector_type(4)));

// ---------------- Kernel A1: random-feature projection -> phi (fp16) + row norms ----------------
__global__ __launch_bounds__(256) void proj_phi(
    const float* __restrict__ qg, const float* __restrict__ kg,
    const float* __restrict__ Wg, const float* __restrict__ bg,
    __half* __restrict__ phiq, __half* __restrict__ phik,
    float* __restrict__ qn, float* __restrict__ kn) {
  int wave = threadIdx.x >> 6, lane = threadIdx.x & 63;
  long row = (long)blockIdx.x * 4 + wave;          // 0 .. BH*S-1
  const float* src = blockIdx.y ? kg : qg;
  __half* dphi = blockIdx.y ? phik : phiq;
  float* dn = blockIdx.y ? kn : qn;
  float myv = src[row * 64 + lane];
  float nn = myv * myv;
  #pragma unroll
  for (int off = 32; off; off >>= 1) nn += __shfl_xor(nn, off);
  float wq = bg[lane];
  #pragma unroll 16
  for (int d = 0; d < 64; ++d)
    wq = fmaf(__shfl(myv, d), Wg[d * 64 + lane], wq);
  float sv, cv;
  __sincosf(wq, &sv, &cv);
  dphi[row * 128 + lane] = __float2half(cv);
  dphi[row * 128 + 64 + lane] = __float2half(sv);
  if (lane == 0) dn[row] = nn;
}

// ---------------- Kernel A2: transpose V -> vt[bh][d][s] (fp16) ----------------
__global__ __launch_bounds__(256) void transpose_v(const float* __restrict__ v,
                                                   __half* __restrict__ vt) {
  int bh = blockIdx.y;
  int s0 = blockIdx.x * 64;
  __shared__ float t[64][65];
  int tid = threadIdx.x;
  const float* base = v + ((long)bh * SEQ + s0) * 64;
  #pragma unroll
  for (int i = 0; i < 4; ++i) {
    int seg = i * 256 + tid;                // 1024 segs of 4 floats
    int srow = seg >> 4, sc4 = (seg & 15) << 2;
    float4 x = *(const float4*)(base + srow * 64 + sc4);
    t[srow][sc4 + 0] = x.x; t[srow][sc4 + 1] = x.y;
    t[srow][sc4 + 2] = x.z; t[srow][sc4 + 3] = x.w;
  }
  __syncthreads();
  int d = tid >> 2, sc = (tid & 3) << 4;
  __half tmp[16];
  #pragma unroll
  for (int j = 0; j < 16; ++j) tmp[j] = __float2half(t[sc + j][d]);
  __half* dst = vt + ((long)bh * 64 + d) * SEQ + s0 + sc;
  *(uint4*)dst = *(uint4*)&tmp[0];
  *(uint4*)(dst + 8) = *(uint4*)&tmp[8];
}

// ---------------- Kernel B: flash attention over transformed scores ----------------
__global__ __launch_bounds__(256, 2) void attn_kernel(
    const __half* __restrict__ phiq_g, const __half* __restrict__ phik_g,
    const __half* __restrict__ vt_g, const float* __restrict__ qn_g,
    const float* __restrict__ kn_g, float* __restrict__ out) {
  const int bh = blockIdx.y;
  const int qb = (int)(gridDim.x - 1 - blockIdx.x);   // heavy blocks first
  const int wave = threadIdx.x >> 6;
  const int lane = threadIdx.x & 63;
  const int g = lane >> 4, ql = lane & 15;
  const long rowbase = (long)bh * SEQ;

  __shared__ __align__(16) __half phik_l[64 * 128];   // swizzled
  __shared__ __align__(16) __half vt_l[64 * 64];      // swizzled
  __shared__ __align__(16) __half p_l[4][32 * 72];    // per-wave P, stride 72
  __shared__ float kn_l[64];
  __shared__ float corr_l[4][32];
  __shared__ float sum_l[4][32];

  const int wq0 = qb * 128 + wave * 32;

  // B-fragments of phi_q (held in registers across all tiles)
  f16x8 bq[2][4];
  #pragma unroll
  for (int qt = 0; qt < 2; ++qt) {
    const __half* p = phiq_g + (rowbase + wq0 + qt * 16 + ql) * 128 + g * 8;
    #pragma unroll
    for (int ks = 0; ks < 4; ++ks) bq[qt][ks] = *(const f16x8*)(p + ks * 32);
  }
  float qn0 = qn_g[rowbase + wq0 + ql];
  float qn1 = qn_g[rowbase + wq0 + 16 + ql];

  float m[2] = {-__builtin_inff(), -__builtin_inff()};
  float lsum[2] = {0.f, 0.f};
  f32x4 acc[2][4] = {};   // [qt][dt]

  const int ntiles = 2 * qb + 2;
  for (int t = 0; t < ntiles; ++t) {
    __syncthreads();
    // ---- stage phik tile (64x128 f16, 16KB), vt tile (64x64 f16, 8KB), kn ----
    {
      const int tid = threadIdx.x;
      const __half* src = phik_g + (rowbase + t * 64) * 128;
      #pragma unroll
      for (int i = 0; i < 4; ++i) {
        int seg = i * 256 + tid;          // 1024 segs of 8 halves
        int key = seg >> 4;
        uint4 x = *(const uint4*)(src + seg * 8);
        int idx = (seg * 8) ^ ((key & 7) << 3);
        *(uint4*)&phik_l[idx] = x;
      }
      const __half* vs = vt_g + (long)bh * 64 * SEQ + t * 64;
      #pragma unroll
      for (int i = 0; i < 2; ++i) {
        int seg = i * 256 + tid;          // 512 segs of 8 halves
        int d = seg >> 3, sc = seg & 7;
        uint4 x = *(const uint4*)(vs + (long)d * SEQ + sc * 8);
        int idx = (d * 64 + sc * 8) ^ ((d & 7) << 3);
        *(uint4*)&vt_l[idx] = x;
      }
      if (tid < 64) kn_l[tid] = kn_g[rowbase + t * 64 + tid];
    }
    __syncthreads();

    // ---- scores: S^T = phik_tile[64x128] x phiq^T[128x16] per wave q-subtile ----
    f32x4 sacc[2][4] = {};
    #pragma unroll
    for (int ks = 0; ks < 4; ++ks) {
      f16x8 a[4];
      #pragma unroll
      for (int kt = 0; kt < 4; ++kt) {
        int idx = ((kt * 16 + ql) * 128 + ks * 32 + g * 8) ^ ((ql & 7) << 3);
        a[kt] = *(const f16x8*)&phik_l[idx];
      }
      #pragma unroll
      for (int qt = 0; qt < 2; ++qt)
        #pragma unroll
        for (int kt = 0; kt < 4; ++kt)
          sacc[qt][kt] = __builtin_amdgcn_mfma_f32_16x16x32_f16(a[kt], bq[qt][ks], sacc[qt][kt], 0, 0, 0);
    }

    // ---- transform + online softmax (lane owns q-column = ql per subtile) ----
    float kn4[4][4];
    #pragma unroll
    for (int kt = 0; kt < 4; ++kt) {
      f32x4 kk = *(const f32x4*)&kn_l[kt * 16 + g * 4];
      kn4[kt][0] = kk[0]; kn4[kt][1] = kk[1]; kn4[kt][2] = kk[2]; kn4[kt][3] = kk[3];
    }
    #pragma unroll
    for (int qt = 0; qt < 2; ++qt) {
      int qrow = wq0 + qt * 16 + ql;
      float qnv = qt ? qn1 : qn0;
      float p[16];
      float tm = -__builtin_inff();
      #pragma unroll
      for (int kt = 0; kt < 4; ++kt)
        #pragma unroll
        for (int r = 0; r < 4; ++r) {
          int key = t * 64 + kt * 16 + g * 4 + r;
          float s = sacc[qt][kt][r] * 0.015625f;          // /64
          float pre = __logf(fmaf(s, s, 1e-5f)) + (qnv + kn4[kt][r]) * 0.0625f;
          pre = (key <= qrow) ? pre : -__builtin_inff();
          p[kt * 4 + r] = pre;
          tm = fmaxf(tm, pre);
        }
      tm = fmaxf(tm, __shfl_xor(tm, 16));
      tm = fmaxf(tm, __shfl_xor(tm, 32));
      float mnew = fmaxf(m[qt], tm);
      float corr = __expf(m[qt] - mnew);
      m[qt] = mnew;
      float ps = 0.f;
      #pragma unroll
      for (int i = 0; i < 16; ++i) { float e = __expf(p[i] - mnew); p[i] = e; ps += e; }
      ps += __shfl_xor(ps, 16);
      ps += __shfl_xor(ps, 32);
      lsum[qt] = lsum[qt] * corr + ps;
      if (g == 0) corr_l[wave][qt * 16 + ql] = corr;
      #pragma unroll
      for (int kt = 0; kt < 4; ++kt) {
        __half h[4];
        #pragma unroll
        for (int r = 0; r < 4; ++r) h[r] = __float2half(p[kt * 4 + r]);
        *(uint2*)&p_l[wave][(qt * 16 + ql) * 72 + kt * 16 + g * 4] = *(uint2*)h;
      }
    }
    __syncthreads();

    // ---- PV: acc += P[16x64] x V[64x16] per (qt, dt) ----
    #pragma unroll
    for (int qt = 0; qt < 2; ++qt) {
      f32x4 c4 = *(const f32x4*)&corr_l[wave][qt * 16 + g * 4];
      #pragma unroll
      for (int dt = 0; dt < 4; ++dt)
        #pragma unroll
        for (int r = 0; r < 4; ++r) acc[qt][dt][r] *= c4[r];
    }
    #pragma unroll
    for (int ks2 = 0; ks2 < 2; ++ks2) {
      f16x8 bv[4];
      #pragma unroll
      for (int dt = 0; dt < 4; ++dt) {
        int idx = ((dt * 16 + ql) * 64 + ks2 * 32 + g * 8) ^ ((ql & 7) << 3);
        bv[dt] = *(const f16x8*)&vt_l[idx];
      }
      #pragma unroll
      for (int qt = 0; qt < 2; ++qt) {
        f16x8 pa = *(const f16x8*)&p_l[wave][(qt * 16 + ql) * 72 + ks2 * 32 + g * 8];
        #pragma unroll
        for (int dt = 0; dt < 4; ++dt)
          acc[qt][dt] = __builtin_amdgcn_mfma_f32_16x16x32_f16(pa, bv[dt], acc[qt][dt], 0, 0, 0);
      }
    }
  }

  // ---- epilogue: normalize + store ----
  if (g == 0) { sum_l[wave][ql] = lsum[0]; sum_l[wave][16 + ql] = lsum[1]; }
  __syncthreads();
  #pragma unroll
  for (int qt = 0; qt < 2; ++qt) {
    f32x4 l4 = *(const f32x4*)&sum_l[wave][qt * 16 + g * 4];
    #pragma unroll
    for (int r = 0; r < 4; ++r) {
      float inv = __builtin_amdgcn_rcpf(l4[r]);
      long row = rowbase + wq0 + qt * 16 + g * 4 + r;
      float* o = out + row * 64 + ql;
      #pragma unroll
      for (int dt = 0; dt < 4; ++dt) o[dt * 16] = acc[qt][dt][r] * inv;
    }
  }
}

extern "C" void kernel_launch(void* const* d_in, const int* in_sizes, int n_in,
                              void* d_out, int out_size, void* d_ws, size_t ws_size,
                              hipStream_t stream) {
  const float* q = (const float*)d_in[0];
  const float* k = (const float*)d_in[1];
  const float* v = (const float*)d_in[2];
  // d_in[3] = mask (causal tril; applied analytically)
  const float* W = (const float*)d_in[4];
  const float* b = (const float*)d_in[5];
  float* out = (float*)d_out;

  char* ws = (char*)d_ws;
  __half* phiq = (__half*)ws;                                   // 16 MB
  __half* phik = (__half*)(ws + 16777216);                      // 16 MB
  __half* vt   = (__half*)(ws + 2 * 16777216);                  // 8 MB
  float* qn = (float*)(ws + 2 * 16777216 + 8388608);
  float* kn = qn + NBH * SEQ;

  proj_phi<<<dim3(NBH * SEQ / 4, 2), 256, 0, stream>>>(q, k, W, b, phiq, phik, qn, kn);
  transpose_v<<<dim3(SEQ / 64, NBH), 256, 0, stream>>>(v, vt);
  attn_kernel<<<dim3(16, NBH), 256, 0, stream>>>(phiq, phik, vt, qn, kn, out);
}

// Round 2
// 114.863 us; speedup vs baseline: 2.2314x; 2.2314x over previous
//
#include <hip/hip_runtime.h>
#include <hip/hip_fp16.h>

#define SEQ 2048
#define NBH 32
#define C1f 0.09016844005556021f   // 0.0625 * log2(e)
#define NEGI -1e30f

typedef _Float16 f16x8 __attribute__((ext_vector_type(8)));
typedef float f32x4 __attribute__((ext_vector_type(4)));
typedef __attribute__((address_space(1))) const unsigned GASU;
typedef __attribute__((address_space(3))) unsigned LASU;

__device__ __forceinline__ void gll16(const void* g, void* l) {
  __builtin_amdgcn_global_load_lds((GASU*)g, (LASU*)l, 16, 0, 0);
}
__device__ __forceinline__ void gll4(const void* g, void* l) {
  __builtin_amdgcn_global_load_lds((GASU*)g, (LASU*)l, 4, 0, 0);
}

// ---------------- Kernel A: transpose V -> vt[bh][d][s] fp16, + W -> Wt hi/lo fp16 ----------------
__global__ __launch_bounds__(256) void transpose_wt(const float* __restrict__ v,
                                                    const float* __restrict__ Wg,
                                                    __half* __restrict__ vt,
                                                    __half* __restrict__ wth,
                                                    __half* __restrict__ wtl) {
  if (blockIdx.x == SEQ / 64) {           // W prep (one block)
    if (blockIdx.y) return;
    int r = threadIdx.x & 63, dg = threadIdx.x >> 6;
    __half th[16], tl[16];
    #pragma unroll
    for (int j = 0; j < 16; ++j) {
      float w = Wg[(dg * 16 + j) * 64 + r];
      th[j] = __float2half(w);
      tl[j] = __float2half(w - __half2float(th[j]));
    }
    *(uint4*)&wth[r * 64 + dg * 16] = *(uint4*)&th[0];
    *(uint4*)&wth[r * 64 + dg * 16 + 8] = *(uint4*)&th[8];
    *(uint4*)&wtl[r * 64 + dg * 16] = *(uint4*)&tl[0];
    *(uint4*)&wtl[r * 64 + dg * 16 + 8] = *(uint4*)&tl[8];
    return;
  }
  int bh = blockIdx.y;
  int s0 = blockIdx.x * 64;
  __shared__ float t[64][65];
  int tid = threadIdx.x;
  const float* base = v + ((long)bh * SEQ + s0) * 64;
  #pragma unroll
  for (int i = 0; i < 4; ++i) {
    int seg = i * 256 + tid;
    int srow = seg >> 4, sc4 = (seg & 15) << 2;
    float4 x = *(const float4*)(base + srow * 64 + sc4);
    t[srow][sc4 + 0] = x.x; t[srow][sc4 + 1] = x.y;
    t[srow][sc4 + 2] = x.z; t[srow][sc4 + 3] = x.w;
  }
  __syncthreads();
  int d = tid >> 2, sc = (tid & 3) << 4;
  __half tmp[16];
  #pragma unroll
  for (int j = 0; j < 16; ++j) tmp[j] = __float2half(t[sc + j][d]);
  __half* dst = vt + ((long)bh * 64 + d) * SEQ + s0 + sc;
  *(uint4*)dst = *(uint4*)&tmp[0];
  *(uint4*)(dst + 8) = *(uint4*)&tmp[8];
}

// ---------------- Kernel B: MFMA projection -> phi fp16 + scaled norms ----------------
__global__ __launch_bounds__(256) void proj_phi(
    const float* __restrict__ qg, const float* __restrict__ kg,
    const __half* __restrict__ wth, const __half* __restrict__ wtl,
    const float* __restrict__ bg,
    __half* __restrict__ phiq, __half* __restrict__ phik,
    float* __restrict__ qns, float* __restrict__ kns) {
  const int wave = threadIdx.x >> 6, lane = threadIdx.x & 63;
  const int g = lane >> 4, ql = lane & 15;
  const int isk = blockIdx.y;
  const float* src = isk ? kg : qg;
  __half* dphi = isk ? phik : phiq;
  float* dn = isk ? kns : qns;
  const long rowblk = (long)blockIdx.x * 64;

  __shared__ __align__(16) float x_l[64 * 64];

  const float* xb = src + rowblk * 64;
  #pragma unroll
  for (int i = 0; i < 4; ++i) {
    int seg = i * 256 + wave * 64 + lane;
    int row = seg >> 4;
    int off = ((seg & 15) * 4) ^ ((row & 7) << 2);
    gll16(xb + row * 64 + off, &x_l[(i * 256 + wave * 64) * 4]);
  }

  f16x8 bh_[2][4], bl_[2][4];
  #pragma unroll
  for (int rt = 0; rt < 4; ++rt)
    #pragma unroll
    for (int ks = 0; ks < 2; ++ks) {
      bh_[ks][rt] = *(const f16x8*)&wth[(rt * 16 + ql) * 64 + ks * 32 + g * 8];
      bl_[ks][rt] = *(const f16x8*)&wtl[(rt * 16 + ql) * 64 + ks * 32 + g * 8];
    }
  float bias[4];
  #pragma unroll
  for (int rt = 0; rt < 4; ++rt) bias[rt] = bg[rt * 16 + ql];

  __syncthreads();

  const int rl = wave * 16 + ql;
  float xv[16];
  #pragma unroll
  for (int ks = 0; ks < 2; ++ks)
    #pragma unroll
    for (int h = 0; h < 2; ++h) {
      int fi = (rl * 64 + ks * 32 + g * 8 + h * 4) ^ ((ql & 7) << 2);
      f32x4 u = *(const f32x4*)&x_l[fi];
      #pragma unroll
      for (int j = 0; j < 4; ++j) xv[ks * 8 + h * 4 + j] = u[j];
    }
  float nn = 0.f;
  #pragma unroll
  for (int j = 0; j < 16; ++j) nn = fmaf(xv[j], xv[j], nn);
  nn += __shfl_xor(nn, 16);
  nn += __shfl_xor(nn, 32);
  if (g == 0) dn[rowblk + rl] = nn * C1f + (isk ? 0.f : -12.f);

  f16x8 ah[2], al[2];
  #pragma unroll
  for (int ks = 0; ks < 2; ++ks)
    #pragma unroll
    for (int j = 0; j < 8; ++j) {
      float v = xv[ks * 8 + j];
      _Float16 hv = (_Float16)v;
      ah[ks][j] = hv;
      al[ks][j] = (_Float16)(v - (float)hv);
    }

  f32x4 sacc[4] = {};
  #pragma unroll
  for (int ks = 0; ks < 2; ++ks)
    #pragma unroll
    for (int rt = 0; rt < 4; ++rt) {
      sacc[rt] = __builtin_amdgcn_mfma_f32_16x16x32_f16(ah[ks], bh_[ks][rt], sacc[rt], 0, 0, 0);
      sacc[rt] = __builtin_amdgcn_mfma_f32_16x16x32_f16(al[ks], bh_[ks][rt], sacc[rt], 0, 0, 0);
      sacc[rt] = __builtin_amdgcn_mfma_f32_16x16x32_f16(ah[ks], bl_[ks][rt], sacc[rt], 0, 0, 0);
    }

  #pragma unroll
  for (int rt = 0; rt < 4; ++rt)
    #pragma unroll
    for (int i2 = 0; i2 < 4; ++i2) {
      float wq = sacc[rt][i2] + bias[rt];
      float sv, cv;
      __sincosf(wq, &sv, &cv);
      long row = rowblk + wave * 16 + g * 4 + i2;
      dphi[row * 128 + rt * 16 + ql] = __float2half(cv);
      dphi[row * 128 + 64 + rt * 16 + ql] = __float2half(sv);
    }
}

// ---------------- Kernel C: paired-strip flash attention, async dbuf staging ----------------
__global__ __launch_bounds__(256, 2) void attn_kernel(
    const __half* __restrict__ phiq_g, const __half* __restrict__ phik_g,
    const __half* __restrict__ vt_g, const float* __restrict__ qns,
    const float* __restrict__ kns, float* __restrict__ out) {
  const int bh = blockIdx.y;
  const int lo = blockIdx.x, hi = 31 - lo;
  const int wave = threadIdx.x >> 6, lane = threadIdx.x & 63;
  const int g = lane >> 4, ql = lane & 15;
  const long rowbase = (long)bh * SEQ;

  __shared__ __align__(16) __half phik_l[2][64 * 128];  // 32 KB, sigma-row-permuted + XOR-swizzled
  __shared__ __align__(16) __half vt_l[2][64 * 64];     // 16 KB, XOR-swizzled
  __shared__ __align__(16) float kn_l[2][4][64];        // 2 KB, per-wave copies (scaled)
  __shared__ __align__(16) __half p_l[4][32 * 64];      // 16 KB, XOR-swizzled, per-wave
  __shared__ __align__(16) float corr_l[4][32];
  __shared__ __align__(16) float sum_l[4][32];

  const __half* pkb = phik_g + rowbase * 128;
  const __half* vtb = vt_g + (long)bh * 64 * SEQ;
  const float* knb = kns + rowbase;

  auto stage = [&](int t, int bb) {
    const __half* ks = pkb + t * 64 * 128;
    #pragma unroll
    for (int i = 0; i < 4; ++i) {
      int seg = i * 256 + wave * 64 + lane;
      int rho = seg >> 4;
      int sg = ((rho & 12) << 2) | ((rho >> 2) & 12) | (rho & 3);  // swap kt<->g fields
      int off = ((seg & 15) * 8) ^ ((rho & 7) << 3);
      gll16(ks + sg * 128 + off, &phik_l[bb][(i * 256 + wave * 64) * 8]);
    }
    const __half* vs = vtb + t * 64;
    #pragma unroll
    for (int i = 0; i < 2; ++i) {
      int seg = i * 256 + wave * 64 + lane;
      int d = seg >> 3;
      int off = ((seg & 7) * 8) ^ ((d & 7) << 3);
      gll16(vs + (long)d * SEQ + off, &vt_l[bb][(i * 256 + wave * 64) * 8]);
    }
    gll4(knb + t * 64 + lane, &kn_l[bb][wave][0]);
  };

  stage(0, 0);

  const int hq = hi * 64 + wave * 16;
  const int lq = lo * 64 + wave * 16;
  f16x8 bq[2][4];
  #pragma unroll
  for (int ks = 0; ks < 4; ++ks) {
    bq[0][ks] = *(const f16x8*)(phiq_g + (rowbase + hq + ql) * 128 + ks * 32 + g * 8);
    bq[1][ks] = *(const f16x8*)(phiq_g + (rowbase + lq + ql) * 128 + ks * 32 + g * 8);
  }
  const float qs0 = qns[rowbase + hq + ql];
  const float qs1 = qns[rowbase + lq + ql];

  float m[2] = {NEGI, NEGI}, lsum[2] = {0.f, 0.f};
  f32x4 acc[2][4] = {};

  for (int t = 0; t <= hi; ++t) {
    const int bb = t & 1;
    asm volatile("s_waitcnt vmcnt(0)" ::: "memory");
    __builtin_amdgcn_s_barrier();
    __builtin_amdgcn_sched_barrier(0);
    if (t < hi) stage(t + 1, bb ^ 1);

    const bool both = (t <= lo);

    // ---- scores: S^T = phik_tile x phiq^T ----
    f32x4 s0[4] = {}, s1[4] = {};
    if (both) {
      #pragma unroll
      for (int ks = 0; ks < 4; ++ks) {
        f16x8 a[4];
        #pragma unroll
        for (int kt = 0; kt < 4; ++kt) {
          int idx = ((kt * 16 + ql) * 128 + ks * 32 + g * 8) ^ ((ql & 7) << 3);
          a[kt] = *(const f16x8*)&phik_l[bb][idx];
        }
        #pragma unroll
        for (int kt = 0; kt < 4; ++kt)
          s0[kt] = __builtin_amdgcn_mfma_f32_16x16x32_f16(a[kt], bq[0][ks], s0[kt], 0, 0, 0);
        #pragma unroll
        for (int kt = 0; kt < 4; ++kt)
          s1[kt] = __builtin_amdgcn_mfma_f32_16x16x32_f16(a[kt], bq[1][ks], s1[kt], 0, 0, 0);
      }
    } else {
      #pragma unroll
      for (int ks = 0; ks < 4; ++ks) {
        f16x8 a[4];
        #pragma unroll
        for (int kt = 0; kt < 4; ++kt) {
          int idx = ((kt * 16 + ql) * 128 + ks * 32 + g * 8) ^ ((ql & 7) << 3);
          a[kt] = *(const f16x8*)&phik_l[bb][idx];
        }
        #pragma unroll
        for (int kt = 0; kt < 4; ++kt)
          s0[kt] = __builtin_amdgcn_mfma_f32_16x16x32_f16(a[kt], bq[0][ks], s0[kt], 0, 0, 0);
      }
    }

    float kn4[4][4];
    #pragma unroll
    for (int kt = 0; kt < 4; ++kt) {
      f32x4 kk = *(const f32x4*)&kn_l[bb][wave][g * 16 + kt * 4];
      kn4[kt][0] = kk[0]; kn4[kt][1] = kk[1]; kn4[kt][2] = kk[2]; kn4[kt][3] = kk[3];
    }
    const int keyb = t * 64 + g * 16;

    auto transform = [&](f32x4 (&sc)[4], float qs, int qrow, float& mr, float& lr, int prow) {
      float pr[16];
      float tm = NEGI;
      #pragma unroll
      for (int kt = 0; kt < 4; ++kt)
        #pragma unroll
        for (int r = 0; r < 4; ++r) {
          float dot = sc[kt][r];
          float pre = __log2f(fmaf(dot, dot, 0.04096f)) + (qs + kn4[kt][r]);
          pre = (keyb + kt * 4 + r <= qrow) ? pre : NEGI;
          pr[kt * 4 + r] = pre;
          tm = fmaxf(tm, pre);
        }
      tm = fmaxf(tm, __shfl_xor(tm, 16));
      tm = fmaxf(tm, __shfl_xor(tm, 32));
      float mn = fmaxf(mr, tm);
      float corr = exp2f(mr - mn);
      mr = mn;
      float ps = 0.f;
      unsigned u[8];
      #pragma unroll
      for (int i = 0; i < 8; ++i) {
        float e0 = exp2f(pr[2 * i] - mn), e1 = exp2f(pr[2 * i + 1] - mn);
        ps += e0 + e1;
        __half2 h = __floats2half2_rn(e0, e1);
        u[i] = *(unsigned*)&h;
      }
      ps += __shfl_xor(ps, 16);
      ps += __shfl_xor(ps, 32);
      lr = lr * corr + ps;
      if (g == 0) corr_l[wave][prow] = corr;
      int swz = (prow & 7) << 3;
      int base = prow * 64 + g * 16;
      *(uint4*)&p_l[wave][base ^ swz] = make_uint4(u[0], u[1], u[2], u[3]);
      *(uint4*)&p_l[wave][(base + 8) ^ swz] = make_uint4(u[4], u[5], u[6], u[7]);
    };

    transform(s0, qs0, hq + ql, m[0], lsum[0], ql);
    if (both) transform(s1, qs1, lq + ql, m[1], lsum[1], 16 + ql);

    // ---- PV ----
    {
      f32x4 c0 = *(const f32x4*)&corr_l[wave][g * 4];
      #pragma unroll
      for (int dt = 0; dt < 4; ++dt)
        #pragma unroll
        for (int r = 0; r < 4; ++r) acc[0][dt][r] *= c0[r];
      if (both) {
        f32x4 c1 = *(const f32x4*)&corr_l[wave][16 + g * 4];
        #pragma unroll
        for (int dt = 0; dt < 4; ++dt)
          #pragma unroll
          for (int r = 0; r < 4; ++r) acc[1][dt][r] *= c1[r];
      }
      #pragma unroll
      for (int ks2 = 0; ks2 < 2; ++ks2) {
        f16x8 bv[4];
        #pragma unroll
        for (int dt = 0; dt < 4; ++dt) {
          int idx = ((dt * 16 + ql) * 64 + ks2 * 32 + g * 8) ^ ((ql & 7) << 3);
          bv[dt] = *(const f16x8*)&vt_l[bb][idx];
        }
        f16x8 pa0 = *(const f16x8*)&p_l[wave][(ql * 64 + ks2 * 32 + g * 8) ^ ((ql & 7) << 3)];
        #pragma unroll
        for (int dt = 0; dt < 4; ++dt)
          acc[0][dt] = __builtin_amdgcn_mfma_f32_16x16x32_f16(pa0, bv[dt], acc[0][dt], 0, 0, 0);
        if (both) {
          f16x8 pa1 = *(const f16x8*)&p_l[wave][((16 + ql) * 64 + ks2 * 32 + g * 8) ^ (((16 + ql) & 7) << 3)];
          #pragma unroll
          for (int dt = 0; dt < 4; ++dt)
            acc[1][dt] = __builtin_amdgcn_mfma_f32_16x16x32_f16(pa1, bv[dt], acc[1][dt], 0, 0, 0);
        }
      }
    }
  }

  // ---- epilogue ----
  if (g == 0) {
    sum_l[wave][ql] = lsum[0];
    sum_l[wave][16 + ql] = lsum[1];
  }
  #pragma unroll
  for (int qt = 0; qt < 2; ++qt) {
    f32x4 l4 = *(const f32x4*)&sum_l[wave][qt * 16 + g * 4];
    int qb = qt ? lq : hq;
    #pragma unroll
    for (int r = 0; r < 4; ++r) {
      float inv = __builtin_amdgcn_rcpf(l4[r]);
      float* o = out + (rowbase + qb + g * 4 + r) * 64 + ql;
      #pragma unroll
      for (int dt = 0; dt < 4; ++dt) o[dt * 16] = acc[qt][dt][r] * inv;
    }
  }
  asm volatile("s_waitcnt vmcnt(0)" ::: "memory");
}

extern "C" void kernel_launch(void* const* d_in, const int* in_sizes, int n_in,
                              void* d_out, int out_size, void* d_ws, size_t ws_size,
                              hipStream_t stream) {
  const float* q = (const float*)d_in[0];
  const float* k = (const float*)d_in[1];
  const float* v = (const float*)d_in[2];
  // d_in[3] = causal mask (applied analytically)
  const float* W = (const float*)d_in[4];
  const float* b = (const float*)d_in[5];
  float* out = (float*)d_out;

  char* ws = (char*)d_ws;
  __half* phiq = (__half*)ws;                          // 16 MB
  __half* phik = (__half*)(ws + 16777216);             // 16 MB
  __half* vt = (__half*)(ws + 33554432);               // 8 MB
  float* qns = (float*)(ws + 41943040);                // 256 KB
  float* kns = qns + NBH * SEQ;                        // 256 KB
  __half* wth = (__half*)(ws + 41943040 + 524288);     // 8 KB
  __half* wtl = wth + 64 * 64;                         // 8 KB

  transpose_wt<<<dim3(SEQ / 64 + 1, NBH), 256, 0, stream>>>(v, W, vt, wth, wtl);
  proj_phi<<<dim3(NBH * SEQ / 64, 2), 256, 0, stream>>>(q, k, wth, wtl, b, phiq, phik, qns, kns);
  attn_kernel<<<dim3(16, NBH), 256, 0, stream>>>(phiq, phik, vt, qns, kns, out);
}

// Round 3
// 99.004 us; speedup vs baseline: 2.5889x; 1.1602x over previous
//
#include <hip/hip_runtime.h>
#include <hip/hip_fp16.h>

#define SEQ 2048
#define NBH 32
#define C1f 0.09016844005556021f   // log2(e)/16

typedef _Float16 f16x8 __attribute__((ext_vector_type(8)));
typedef float f32x4 __attribute__((ext_vector_type(4)));
typedef __attribute__((address_space(1))) const unsigned GASU;
typedef __attribute__((address_space(3))) unsigned LASU;

__device__ __forceinline__ void gll16(const void* g, void* l) {
  __builtin_amdgcn_global_load_lds((GASU*)g, (LASU*)l, 16, 0, 0);
}
__device__ __forceinline__ void gll4(const void* g, void* l) {
  __builtin_amdgcn_global_load_lds((GASU*)g, (LASU*)l, 4, 0, 0);
}

// ---------------- Kernel A: transpose V -> vt[bh][d][s] fp16, + W -> Wt hi/lo fp16 ----------------
__global__ __launch_bounds__(256) void transpose_wt(const float* __restrict__ v,
                                                    const float* __restrict__ Wg,
                                                    __half* __restrict__ vt,
                                                    __half* __restrict__ wth,
                                                    __half* __restrict__ wtl) {
  if (blockIdx.x == SEQ / 64) {           // W prep (one block)
    if (blockIdx.y) return;
    int r = threadIdx.x & 63, dg = threadIdx.x >> 6;
    __half th[16], tl[16];
    #pragma unroll
    for (int j = 0; j < 16; ++j) {
      float w = Wg[(dg * 16 + j) * 64 + r];
      th[j] = __float2half(w);
      tl[j] = __float2half(w - __half2float(th[j]));
    }
    *(uint4*)&wth[r * 64 + dg * 16] = *(uint4*)&th[0];
    *(uint4*)&wth[r * 64 + dg * 16 + 8] = *(uint4*)&th[8];
    *(uint4*)&wtl[r * 64 + dg * 16] = *(uint4*)&tl[0];
    *(uint4*)&wtl[r * 64 + dg * 16 + 8] = *(uint4*)&tl[8];
    return;
  }
  int bh = blockIdx.y;
  int s0 = blockIdx.x * 64;
  __shared__ float t[64][65];
  int tid = threadIdx.x;
  const float* base = v + ((long)bh * SEQ + s0) * 64;
  #pragma unroll
  for (int i = 0; i < 4; ++i) {
    int seg = i * 256 + tid;
    int srow = seg >> 4, sc4 = (seg & 15) << 2;
    float4 x = *(const float4*)(base + srow * 64 + sc4);
    t[srow][sc4 + 0] = x.x; t[srow][sc4 + 1] = x.y;
    t[srow][sc4 + 2] = x.z; t[srow][sc4 + 3] = x.w;
  }
  __syncthreads();
  int d = tid >> 2, sc = (tid & 3) << 4;
  __half tmp[16];
  #pragma unroll
  for (int j = 0; j < 16; ++j) tmp[j] = __float2half(t[sc + j][d]);
  __half* dst = vt + ((long)bh * 64 + d) * SEQ + s0 + sc;
  *(uint4*)dst = *(uint4*)&tmp[0];
  *(uint4*)(dst + 8) = *(uint4*)&tmp[8];
}

// ---------------- Kernel B: MFMA projection -> phi/8 fp16 + ekn = e^{||k||^2/16} ----------------
__global__ __launch_bounds__(256) void proj_phi(
    const float* __restrict__ qg, const float* __restrict__ kg,
    const __half* __restrict__ wth, const __half* __restrict__ wtl,
    const float* __restrict__ bg,
    __half* __restrict__ phiq, __half* __restrict__ phik,
    float* __restrict__ kns) {
  const int wave = threadIdx.x >> 6, lane = threadIdx.x & 63;
  const int g = lane >> 4, ql = lane & 15;
  const int isk = blockIdx.y;
  const float* src = isk ? kg : qg;
  __half* dphi = isk ? phik : phiq;
  const long rowblk = (long)blockIdx.x * 64;

  __shared__ __align__(16) float x_l[64 * 64];

  const float* xb = src + rowblk * 64;
  #pragma unroll
  for (int i = 0; i < 4; ++i) {
    int seg = i * 256 + wave * 64 + lane;
    int row = seg >> 4;
    int off = ((seg & 15) * 4) ^ ((row & 7) << 2);
    gll16(xb + row * 64 + off, &x_l[(i * 256 + wave * 64) * 4]);
  }

  f16x8 bh_[2][4], bl_[2][4];
  #pragma unroll
  for (int rt = 0; rt < 4; ++rt)
    #pragma unroll
    for (int ks = 0; ks < 2; ++ks) {
      bh_[ks][rt] = *(const f16x8*)&wth[(rt * 16 + ql) * 64 + ks * 32 + g * 8];
      bl_[ks][rt] = *(const f16x8*)&wtl[(rt * 16 + ql) * 64 + ks * 32 + g * 8];
    }
  float bias[4];
  #pragma unroll
  for (int rt = 0; rt < 4; ++rt) bias[rt] = bg[rt * 16 + ql];

  __syncthreads();

  const int rl = wave * 16 + ql;
  float xv[16];
  #pragma unroll
  for (int ks = 0; ks < 2; ++ks)
    #pragma unroll
    for (int h = 0; h < 2; ++h) {
      int fi = (rl * 64 + ks * 32 + g * 8 + h * 4) ^ ((ql & 7) << 2);
      f32x4 u = *(const f32x4*)&x_l[fi];
      #pragma unroll
      for (int j = 0; j < 4; ++j) xv[ks * 8 + h * 4 + j] = u[j];
    }
  if (isk) {
    float nn = 0.f;
    #pragma unroll
    for (int j = 0; j < 16; ++j) nn = fmaf(xv[j], xv[j], nn);
    nn += __shfl_xor(nn, 16);
    nn += __shfl_xor(nn, 32);
    if (g == 0) kns[rowblk + rl] = exp2f(nn * C1f);
  }

  f16x8 ah[2], al[2];
  #pragma unroll
  for (int ks = 0; ks < 2; ++ks)
    #pragma unroll
    for (int j = 0; j < 8; ++j) {
      float v = xv[ks * 8 + j];
      _Float16 hv = (_Float16)v;
      ah[ks][j] = hv;
      al[ks][j] = (_Float16)(v - (float)hv);
    }

  f32x4 sacc[4] = {};
  #pragma unroll
  for (int ks = 0; ks < 2; ++ks)
    #pragma unroll
    for (int rt = 0; rt < 4; ++rt) {
      sacc[rt] = __builtin_amdgcn_mfma_f32_16x16x32_f16(ah[ks], bh_[ks][rt], sacc[rt], 0, 0, 0);
      sacc[rt] = __builtin_amdgcn_mfma_f32_16x16x32_f16(al[ks], bh_[ks][rt], sacc[rt], 0, 0, 0);
      sacc[rt] = __builtin_amdgcn_mfma_f32_16x16x32_f16(ah[ks], bl_[ks][rt], sacc[rt], 0, 0, 0);
    }

  #pragma unroll
  for (int rt = 0; rt < 4; ++rt)
    #pragma unroll
    for (int i2 = 0; i2 < 4; ++i2) {
      float wq = sacc[rt][i2] + bias[rt];
      float sv, cv;
      __sincosf(wq, &sv, &cv);
      long row = rowblk + wave * 16 + g * 4 + i2;
      dphi[row * 128 + rt * 16 + ql] = __float2half(cv * 0.125f);
      dphi[row * 128 + 64 + rt * 16 + ql] = __float2half(sv * 0.125f);
    }
}

// ---------------- Kernel C: 128-q adjacent-block flash attention, linear-domain softmax ----------------
__global__ __launch_bounds__(256, 2) void attn_kernel(
    const __half* __restrict__ phiq_g, const __half* __restrict__ phik_g,
    const __half* __restrict__ vt_g, const float* __restrict__ ekn_g,
    float* __restrict__ out) {
  const int x = blockIdx.x;
  const int bh = ((x & 7) << 2) | ((x >> 3) & 3);      // 4 bh per XCD -> L2 locality
  const int braw = x >> 5;
  const int b = (braw < 8) ? (15 - braw) : (braw - 8); // heavy first; CU pairs sum const
  const int wave = threadIdx.x >> 6, lane = threadIdx.x & 63;
  const int g = lane >> 4, ql = lane & 15;
  const long rowbase = (long)bh * SEQ;
  const int qbase = b * 128 + (3 - wave) * 32;         // waves 0,1 own the top rows

  __shared__ __align__(16) __half phik_l[2][64 * 128]; // 32 KB, sigma-permuted + swizzled
  __shared__ __align__(16) __half vt_l[2][64 * 64];    // 16 KB, swizzled
  __shared__ __align__(16) float ekn_l[2][4][64];      // 2 KB, per-wave copies
  __shared__ __align__(16) __half p_l[4][32 * 64];     // 16 KB, per-wave, swizzled

  const __half* pkb = phik_g + rowbase * 128;
  const __half* vtb = vt_g + (long)bh * 64 * SEQ;
  const float* ekb = ekn_g + rowbase;

  auto stage = [&](int t, int bb) {
    const __half* ks = pkb + t * 64 * 128;
    #pragma unroll
    for (int i = 0; i < 4; ++i) {
      int seg = i * 256 + wave * 64 + lane;
      int rho = seg >> 4;
      int sg = ((rho & 12) << 2) | ((rho >> 2) & 12) | (rho & 3);  // swap kt<->g bit-pairs
      int off = ((seg & 15) * 8) ^ ((rho & 7) << 3);
      gll16(ks + sg * 128 + off, &phik_l[bb][(i * 256 + wave * 64) * 8]);
    }
    const __half* vs = vtb + t * 64;
    #pragma unroll
    for (int i = 0; i < 2; ++i) {
      int seg = i * 256 + wave * 64 + lane;
      int d = seg >> 3;
      int off = ((seg & 7) * 8) ^ ((d & 7) << 3);
      gll16(vs + (long)d * SEQ + off, &vt_l[bb][(i * 256 + wave * 64) * 8]);
    }
    gll4(ekb + t * 64 + lane, &ekn_l[bb][wave][0]);
  };

  stage(0, 0);

  f16x8 bq[2][4];
  #pragma unroll
  for (int c = 0; c < 2; ++c)
    #pragma unroll
    for (int ks = 0; ks < 4; ++ks)
      bq[c][ks] = *(const f16x8*)(phiq_g + (rowbase + qbase + c * 16 + ql) * 128 + ks * 32 + g * 8);

  float M[2] = {0.f, 0.f}, Minv[2] = {0.f, 0.f}, lsum[2] = {0.f, 0.f};
  f32x4 acc[2][4] = {};

  const int ntiles = 2 * b + 2;
  for (int t = 0; t < ntiles; ++t) {
    const int bb = t & 1;
    asm volatile("s_waitcnt vmcnt(0)" ::: "memory");
    __builtin_amdgcn_s_barrier();
    __builtin_amdgcn_sched_barrier(0);
    if (t + 1 < ntiles) stage(t + 1, bb ^ 1);

    const bool skip = (t == 2 * b + 1) && (wave >= 2);   // fully-masked waves on last tile
    if (!skip) {
      // ---- scores: S^T = phik_tile x phiq^T, A-frags reused across both q-chunks ----
      f32x4 s0[4] = {}, s1[4] = {};
      #pragma unroll
      for (int ks = 0; ks < 4; ++ks) {
        f16x8 a[4];
        #pragma unroll
        for (int kt = 0; kt < 4; ++kt) {
          int idx = ((kt * 16 + ql) * 128 + ks * 32 + g * 8) ^ ((ql & 7) << 3);
          a[kt] = *(const f16x8*)&phik_l[bb][idx];
        }
        #pragma unroll
        for (int kt = 0; kt < 4; ++kt)
          s0[kt] = __builtin_amdgcn_mfma_f32_16x16x32_f16(a[kt], bq[0][ks], s0[kt], 0, 0, 0);
        #pragma unroll
        for (int kt = 0; kt < 4; ++kt)
          s1[kt] = __builtin_amdgcn_mfma_f32_16x16x32_f16(a[kt], bq[1][ks], s1[kt], 0, 0, 0);
      }

      float ek[4][4];
      #pragma unroll
      for (int kt = 0; kt < 4; ++kt) {
        f32x4 e = *(const f32x4*)&ekn_l[bb][wave][g * 16 + kt * 4];
        ek[kt][0] = e[0]; ek[kt][1] = e[1]; ek[kt][2] = e[2]; ek[kt][3] = e[3];
      }
      const int keyb = t * 64 + g * 16;

      auto transform = [&](f32x4 (&sc)[4], int c) {
        const int qrow = qbase + c * 16 + ql;
        const bool domask = (t * 64 + 63) > (qbase + c * 16);
        float p[16];
        float tm = 0.f;
        #pragma unroll
        for (int kt = 0; kt < 4; ++kt)
          #pragma unroll
          for (int r = 0; r < 4; ++r) {
            float d = sc[kt][r];
            float pv = fmaf(d, d, 1e-5f) * ek[kt][r];   // (energy^2+eps)*e^{kn}; qn cancels
            if (domask) pv = (keyb + kt * 4 + r <= qrow) ? pv : 0.f;
            p[kt * 4 + r] = pv;
            tm = fmaxf(tm, pv);
          }
        tm = fmaxf(tm, __shfl_xor(tm, 16));
        tm = fmaxf(tm, __shfl_xor(tm, 32));
        if (__any(tm > M[c] * 16.f)) {                   // defer-rescale (T13)
          float mq = __uint_as_float(__float_as_uint(tm) & 0xFF800000u);  // pow2 floor
          float Mn = fmaxf(M[c], mq);
          float nI = __builtin_amdgcn_rcpf(Mn);          // exact for pow2
          float corr = M[c] * nI;                        // exact pow2 ratio (0 on first)
          M[c] = Mn; Minv[c] = nI;
          lsum[c] *= corr;
          float c4[4];
          #pragma unroll
          for (int r = 0; r < 4; ++r) c4[r] = __shfl(corr, (lane & 48) | (g * 4 + r));
          #pragma unroll
          for (int dt = 0; dt < 4; ++dt)
            #pragma unroll
            for (int r = 0; r < 4; ++r) acc[c][dt][r] *= c4[r];
        }
        const float iv = Minv[c];
        float ps = 0.f;
        unsigned u[8];
        #pragma unroll
        for (int i = 0; i < 8; ++i) {
          float e0 = p[2 * i] * iv, e1 = p[2 * i + 1] * iv;
          ps += e0 + e1;
          __half2 h = __floats2half2_rn(e0, e1);
          u[i] = *(unsigned*)&h;
        }
        ps += __shfl_xor(ps, 16);
        ps += __shfl_xor(ps, 32);
        lsum[c] += ps;
        int prow = c * 16 + ql;
        int swz = (prow & 7) << 3;
        int base = prow * 64 + g * 16;
        *(uint4*)&p_l[wave][base ^ swz] = make_uint4(u[0], u[1], u[2], u[3]);
        *(uint4*)&p_l[wave][(base + 8) ^ swz] = make_uint4(u[4], u[5], u[6], u[7]);
      };

      transform(s0, 0);
      transform(s1, 1);

      // ---- PV ----
      #pragma unroll
      for (int ks2 = 0; ks2 < 2; ++ks2) {
        f16x8 bv[4];
        #pragma unroll
        for (int dt = 0; dt < 4; ++dt) {
          int idx = ((dt * 16 + ql) * 64 + ks2 * 32 + g * 8) ^ ((ql & 7) << 3);
          bv[dt] = *(const f16x8*)&vt_l[bb][idx];
        }
        f16x8 pa0 = *(const f16x8*)&p_l[wave][(ql * 64 + ks2 * 32 + g * 8) ^ ((ql & 7) << 3)];
        f16x8 pa1 = *(const f16x8*)&p_l[wave][((16 + ql) * 64 + ks2 * 32 + g * 8) ^ (((16 + ql) & 7) << 3)];
        #pragma unroll
        for (int dt = 0; dt < 4; ++dt)
          acc[0][dt] = __builtin_amdgcn_mfma_f32_16x16x32_f16(pa0, bv[dt], acc[0][dt], 0, 0, 0);
        #pragma unroll
        for (int dt = 0; dt < 4; ++dt)
          acc[1][dt] = __builtin_amdgcn_mfma_f32_16x16x32_f16(pa1, bv[dt], acc[1][dt], 0, 0, 0);
      }
    }
  }

  // ---- epilogue: normalize + store (all register/shfl, no barrier) ----
  #pragma unroll
  for (int c = 0; c < 2; ++c) {
    #pragma unroll
    for (int r = 0; r < 4; ++r) {
      float ls = __shfl(lsum[c], (lane & 48) | (g * 4 + r));
      float inv = __builtin_amdgcn_rcpf(ls);
      float* o = out + (rowbase + qbase + c * 16 + g * 4 + r) * 64 + ql;
      #pragma unroll
      for (int dt = 0; dt < 4; ++dt) o[dt * 16] = acc[c][dt][r] * inv;
    }
  }
}

extern "C" void kernel_launch(void* const* d_in, const int* in_sizes, int n_in,
                              void* d_out, int out_size, void* d_ws, size_t ws_size,
                              hipStream_t stream) {
  const float* q = (const float*)d_in[0];
  const float* k = (const float*)d_in[1];
  const float* v = (const float*)d_in[2];
  // d_in[3] = causal mask (applied analytically)
  const float* W = (const float*)d_in[4];
  const float* b = (const float*)d_in[5];
  float* out = (float*)d_out;

  char* ws = (char*)d_ws;
  __half* phiq = (__half*)ws;                          // 16 MB
  __half* phik = (__half*)(ws + 16777216);             // 16 MB
  __half* vt = (__half*)(ws + 33554432);               // 8 MB
  float* ekn = (float*)(ws + 41943040);                // 256 KB
  __half* wth = (__half*)(ws + 41943040 + 262144);     // 8 KB
  __half* wtl = wth + 64 * 64;                         // 8 KB

  transpose_wt<<<dim3(SEQ / 64 + 1, NBH), 256, 0, stream>>>(v, W, vt, wth, wtl);
  proj_phi<<<dim3(NBH * SEQ / 64, 2), 256, 0, stream>>>(q, k, wth, wtl, b, phiq, phik, ekn);
  attn_kernel<<<dim3(512), 256, 0, stream>>>(phiq, phik, vt, ekn, out);
}